// Round 4
// baseline (202.805 us; speedup 1.0000x reference)
//
#include <hip/hip_runtime.h>

#define B_   4
#define S_   4096
#define NC   8192
#define C_   512
#define CS   256
#define KTOT 768

typedef __attribute__((ext_vector_type(8))) short short8;
typedef __attribute__((ext_vector_type(4))) float f32x4;

// fp32 -> bf16 round-to-nearest-even (finite inputs only)
static __device__ __forceinline__ unsigned short f2bf(float x) {
    unsigned u = __builtin_bit_cast(unsigned, x);
    unsigned r = u + 0x7FFFu + ((u >> 16) & 1u);
    return (unsigned short)(r >> 16);
}

// ================= K1: fused prep (unchanged) =================
// bid 0..63    : beff  | 64..95: wc | 96..159: w1 | 160..287: pad_ref
__global__ __launch_bounds__(256) void prep_kernel(
        const float* __restrict__ rxyz, float4* __restrict__ refpk,
        const float* __restrict__ Wcat, const float* __restrict__ Wseed,
        unsigned short* __restrict__ Wcomb,
        const float* __restrict__ bseed, const float* __restrict__ bcat,
        float* __restrict__ beff) {
    __shared__ float sa[64][68];
    __shared__ float sbt[64][68];
    int bid = blockIdx.x;
    int tid = threadIdx.x;

    if (bid < 64) {
        int w = tid >> 6, l = tid & 63;
        int o = bid * 4 + w;
        float4 wv = *(const float4*)(Wcat + (size_t)o * 512 + 256 + l * 4);
        float4 bb = *(const float4*)(bseed + l * 4);
        float acc = __fmul_rn(wv.x, bb.x);
        acc = fmaf(wv.y, bb.y, acc);
        acc = fmaf(wv.z, bb.z, acc);
        acc = fmaf(wv.w, bb.w, acc);
        #pragma unroll
        for (int off = 32; off > 0; off >>= 1) acc += __shfl_down(acc, off);
        if (l == 0) beff[o] = acc + bcat[o];
    } else if (bid < 96) {
        int xb = bid - 64;
        int tc = (xb & 7) * 64;
        int to = (xb >> 3) * 64;
        int tx = tid & 15, ty = tid >> 4;
        float acc[4][4] = {};
        for (int kt = 0; kt < 256; kt += 64) {
            __syncthreads();
            #pragma unroll
            for (int r = 0; r < 4; ++r) {
                int oo = r * 16 + ty;
                float4 v = *(const float4*)(Wcat + (size_t)(to + oo) * 512 + 256 + kt + tx * 4);
                sa[oo][tx * 4 + 0] = v.x;
                sa[oo][tx * 4 + 1] = v.y;
                sa[oo][tx * 4 + 2] = v.z;
                sa[oo][tx * 4 + 3] = v.w;
                float4 u = *(const float4*)(Wseed + (size_t)(kt + oo) * 512 + tc + tx * 4);
                sbt[oo][tx * 4 + 0] = u.x;
                sbt[oo][tx * 4 + 1] = u.y;
                sbt[oo][tx * 4 + 2] = u.z;
                sbt[oo][tx * 4 + 3] = u.w;
            }
            __syncthreads();
            for (int k = 0; k < 64; ++k) {
                float a[4], bb2[4];
                #pragma unroll
                for (int i = 0; i < 4; ++i) a[i] = sa[ty * 4 + i][k];
                #pragma unroll
                for (int j = 0; j < 4; ++j) bb2[j] = sbt[k][tx * 4 + j];
                #pragma unroll
                for (int i = 0; i < 4; ++i)
                    #pragma unroll
                    for (int j = 0; j < 4; ++j)
                        acc[i][j] = fmaf(a[i], bb2[j], acc[i][j]);
            }
        }
        #pragma unroll
        for (int i = 0; i < 4; ++i)
            #pragma unroll
            for (int j = 0; j < 4; ++j)
                Wcomb[(size_t)(to + ty * 4 + i) * KTOT + 256 + tc + tx * 4 + j] = f2bf(acc[i][j]);
    } else if (bid < 160) {
        int g = ((bid - 96) * 256 + tid) * 4;
        int o = g >> 8, cc = g & 255;
        float4 v = *(const float4*)(Wcat + (size_t)o * 512 + cc);
        ushort4 ov;
        ov.x = f2bf(v.x); ov.y = f2bf(v.y); ov.z = f2bf(v.z); ov.w = f2bf(v.w);
        *(ushort4*)(Wcomb + (size_t)o * KTOT + cc) = ov;
    } else {
        int gid = (bid - 160) * 256 + tid;  // 0..32767
        float x = rxyz[gid * 3 + 0];
        float y = rxyz[gid * 3 + 1];
        float z = rxyz[gid * 3 + 2];
        float r2 = __fadd_rn(__fadd_rn(__fmul_rn(x, x), __fmul_rn(y, y)), __fmul_rn(z, z));
        refpk[gid] = make_float4(x, y, z, r2);
    }
}

// ================= K2: fused argmin + transpose =================
// 4608 blocks: bid%9==0 -> argmin (512 blocks), else transpose (4096).
// Argmin restructured (R3 post-mortem: global-load latency-bound at 23%
// per-wave duty regardless of VGPR tuning): stage the 2048-ref chunk in
// LDS once per block, then every lane broadcast-reads one ref per iter
// (same-address ds_read_b128 = conflict-free) and scores its own 2
// registered queries. Latency to hide: ~120cy LDS per 42 VALU cycles ->
// each wave self-sufficient (~90% duty), occupancy-independent.
// Numerics bit-identical: same per-pair rounding sequence, each ref
// scanned once in ascending index order (strict < = first occurrence),
// cross-wave/cross-chunk merge by (val,idx) lexicographic min.
__global__ __launch_bounds__(256) void mid_kernel(
        const float* __restrict__ qxyz, const float4* __restrict__ refpk,
        float* __restrict__ pval, int* __restrict__ pidx,
        const float* __restrict__ rf, unsigned short* __restrict__ refT) {
    // overlay: argmin { float4 rbuf[2048] (32KB) | msv 2KB | msx 2KB } = 36KB
    //          transpose { float t[64][65] } = 16.6KB
    __shared__ __align__(16) char smem[36864];
    int bid = blockIdx.x;
    int tid = threadIdx.x;

    if (bid % 9 != 0) {
        // ---------- transpose path: (B,C,Nc) fp32 -> (B,Nc,C) bf16 ----------
        float (*t)[65] = (float (*)[65])smem;
        int id = bid - bid / 9 - 1;        // 0..4095
        int b = id >> 10;
        int c0 = ((id >> 7) & 7) * 64;
        int n0 = (id & 127) * 64;
        int tx = tid & 15, ty = tid >> 4;
        #pragma unroll
        for (int r = 0; r < 4; ++r) {
            int cc = r * 16 + ty;
            float4 v = *(const float4*)(rf + ((size_t)b * C_ + c0 + cc) * NC + n0 + tx * 4);
            t[tx * 4 + 0][cc] = v.x;
            t[tx * 4 + 1][cc] = v.y;
            t[tx * 4 + 2][cc] = v.z;
            t[tx * 4 + 3][cc] = v.w;
        }
        __syncthreads();
        #pragma unroll
        for (int r = 0; r < 4; ++r) {
            int n = r * 16 + ty;
            ushort4 o;
            o.x = f2bf(t[n][tx * 4 + 0]);
            o.y = f2bf(t[n][tx * 4 + 1]);
            o.z = f2bf(t[n][tx * 4 + 2]);
            o.w = f2bf(t[n][tx * 4 + 3]);
            *(ushort4*)(refT + ((size_t)b * NC + n0 + n) * C_ + c0 + tx * 4) = o;
        }
    } else {
        // ---------- argmin path: 128 queries x one 2048-ref chunk ----------
        float4* rbuf = (float4*)smem;
        float*  msv  = (float*)(smem + 32768);
        int*    msx  = (int*)(smem + 32768 + 2048);

        int aid  = bid / 9;                // 0..511
        int qgrp = aid & 127;              // global query-group (128 queries)
        int c    = aid >> 7;               // chunk 0..3
        int b    = qgrp >> 5;
        int sb   = (qgrp & 31) * 128;      // s-base within batch
        int lane = tid & 63;
        int w    = tid >> 6;

        // per-lane queries: q0 = sb+lane, q1 = sb+64+lane
        const float* qp0 = qxyz + ((size_t)(b * S_ + sb + lane)) * 3;
        float qx0 = qp0[0], qy0 = qp0[1], qz0 = qp0[2];
        const float* qp1 = qp0 + 64 * 3;
        float qx1 = qp1[0], qy1 = qp1[1], qz1 = qp1[2];
        float q20 = __fadd_rn(__fadd_rn(__fmul_rn(qx0, qx0), __fmul_rn(qy0, qy0)),
                              __fmul_rn(qz0, qz0));
        float q21 = __fadd_rn(__fadd_rn(__fmul_rn(qx1, qx1), __fmul_rn(qy1, qy1)),
                              __fmul_rn(qz1, qz1));

        // stage chunk refs -> LDS (all loads in flight, then writes)
        const float4* rch = refpk + (size_t)b * NC + c * 2048;
        float4 tmp[8];
        #pragma unroll
        for (int i = 0; i < 8; ++i) tmp[i] = rch[tid + 256 * i];
        #pragma unroll
        for (int i = 0; i < 8; ++i) rbuf[tid + 256 * i] = tmp[i];
        __syncthreads();

        // wave w scans refs [w*512, w*512+512), ascending (first-occurrence)
        const float4* rb = rbuf + w * 512;
        float b0 = 3.4028235e38f, b1 = 3.4028235e38f;
        int j0 = 0, j1 = 0;
        #pragma unroll 4
        for (int t_ = 0; t_ < 512; ++t_) {
            float4 r = rb[t_];                 // broadcast ds_read_b128
            {
                // qr = ((qx*rx + qy*ry) + qz*rz), no FMA (np association)
                float qr = __fadd_rn(__fadd_rn(__fmul_rn(qx0, r.x), __fmul_rn(qy0, r.y)),
                                     __fmul_rn(qz0, r.z));
                float s = __fadd_rn(q20, r.w);
                float d2 = fmaf(qr, -2.0f, s); // same single rounding as fsub(s, qr+qr)
                if (d2 < b0) { b0 = d2; j0 = t_; }
            }
            {
                float qr = __fadd_rn(__fadd_rn(__fmul_rn(qx1, r.x), __fmul_rn(qy1, r.y)),
                                     __fmul_rn(qz1, r.z));
                float s = __fadd_rn(q21, r.w);
                float d2 = fmaf(qr, -2.0f, s);
                if (d2 < b1) { b1 = d2; j1 = t_; }
            }
        }

        // cross-wave merge: ranges ascend with w -> (val, idx) lexicographic
        __syncthreads();                   // rbuf reads done before overwrite? (msv/msx are past 32KB, no overlap; this sync orders partial writes)
        msv[w * 128 + lane]      = b0;
        msv[w * 128 + 64 + lane] = b1;
        msx[w * 128 + lane]      = w * 512 + j0;
        msx[w * 128 + 64 + lane] = w * 512 + j1;
        __syncthreads();
        if (tid < 128) {
            float v = msv[tid];
            int   x = msx[tid];
            #pragma unroll
            for (int ww = 1; ww < 4; ++ww) {
                float vv = msv[ww * 128 + tid];
                int   xx = msx[ww * 128 + tid];
                if (vv < v || (vv == v && xx < x)) { v = vv; x = xx; }
            }
            int qs = b * S_ + sb + tid;
            pval[qs * 4 + c] = v;
            pidx[qs * 4 + c] = c * 2048 + x;
        }
    }
}

// ================= K3: fused merge + gather + GEMM, 2-phase pipelined (unchanged) =================
__global__ __launch_bounds__(256) void fused_gemm_kernel(
        const unsigned short* __restrict__ Wcomb,
        const float* __restrict__ seed,
        const unsigned short* __restrict__ refT,
        const float* __restrict__ pval,
        const int* __restrict__ pidx,
        const float* __restrict__ beff,
        float* __restrict__ out) {
    __shared__ __align__(16) unsigned short sA[2][128][72];
    __shared__ __align__(16) unsigned short sB[2][32][72];
    __shared__ int sIdx[32];
    __shared__ float sBias[128];

    int tid = threadIdx.x;
    int b = blockIdx.z;
    int m0 = blockIdx.y * 128;
    int s0 = blockIdx.x * 32;
    if (tid < 32) {
        int qs = b * S_ + s0 + tid;
        float v = pval[qs * 4 + 0];
        int x = pidx[qs * 4 + 0];
        #pragma unroll
        for (int c = 1; c < 4; ++c) {
            float vv = pval[qs * 4 + c];
            int xx = pidx[qs * 4 + c];
            if (vv < v || (vv == v && xx < x)) { v = vv; x = xx; }
        }
        sIdx[tid] = x & (NC - 1);   // defensive clamp
    }
    if (tid < 128) sBias[tid] = beff[m0 + tid];

    int lane = tid & 63;
    int w = tid >> 6;
    int ln = lane & 15;
    int quad = lane >> 4;
    int q8 = quad * 8;

    int mmb  = tid >> 3;
    int kk8a = (tid & 7) << 3;
    const unsigned short* Arow = Wcomb + (size_t)(m0 + mmb) * KTOT + kk8a;
    int n_s  = tid & 31;
    int kk8s = (tid >> 5) << 3;
    int n_g  = tid >> 3;

    f32x4 acc[2][2];
    #pragma unroll
    for (int i = 0; i < 2; ++i)
        #pragma unroll
        for (int j = 0; j < 2; ++j)
            acc[i][j] = (f32x4){0.f, 0.f, 0.f, 0.f};

    short8 ra[4];
    short8 rb;
    float rbf[8];

    #define SLOAD(PK) do {                                                         \
        int pk0 = (PK) * 64;                                                       \
        _Pragma("unroll")                                                          \
        for (int i = 0; i < 4; ++i)                                                \
            ra[i] = *(const short8*)(Arow + (size_t)i * 32 * KTOT + pk0);          \
        if (pk0 < 256) {                                                           \
            const float* sp = seed + ((size_t)b * CS + pk0 + kk8s) * S_ + s0 + n_s;\
            _Pragma("unroll")                                                      \
            for (int r = 0; r < 8; ++r) rbf[r] = sp[(size_t)r * S_];               \
        } else {                                                                   \
            rb = *(const short8*)(refT + ((size_t)b * NC + sIdx[n_g]) * C_         \
                                  + (pk0 - 256) + kk8a);                           \
        }                                                                          \
    } while (0)

    #define SWRITE(BUF, PK) do {                                                   \
        int pk0 = (PK) * 64;                                                       \
        _Pragma("unroll")                                                          \
        for (int i = 0; i < 4; ++i)                                                \
            *(short8*)&sA[BUF][mmb + 32 * i][kk8a] = ra[i];                        \
        if (pk0 < 256) {                                                           \
            unsigned short tmp[8];                                                 \
            _Pragma("unroll")                                                      \
            for (int r = 0; r < 8; ++r) tmp[r] = f2bf(rbf[r]);                     \
            *(short8*)&sB[BUF][n_s][kk8s] = *(const short8*)tmp;                   \
        } else {                                                                   \
            *(short8*)&sB[BUF][n_g][kk8a] = rb;                                    \
        }                                                                          \
    } while (0)

    SLOAD(0);
    SWRITE(0, 0);
    __syncthreads();

    int cur = 0;
    for (int ks = 0; ks < 12; ++ks) {
        if (ks < 11) SLOAD(ks + 1);
        #pragma unroll
        for (int kf = 0; kf < 2; ++kf) {
            short8 af[2], bfr[2];
            #pragma unroll
            for (int i = 0; i < 2; ++i)
                af[i] = *(const short8*)&sA[cur][w * 32 + i * 16 + ln][kf * 32 + q8];
            #pragma unroll
            for (int j = 0; j < 2; ++j)
                bfr[j] = *(const short8*)&sB[cur][j * 16 + ln][kf * 32 + q8];
            #pragma unroll
            for (int i = 0; i < 2; ++i)
                #pragma unroll
                for (int j = 0; j < 2; ++j)
                    acc[i][j] = __builtin_amdgcn_mfma_f32_16x16x32_bf16(af[i], bfr[j], acc[i][j], 0, 0, 0);
        }
        if (ks < 11) {
            SWRITE(cur ^ 1, ks + 1);
            __syncthreads();
            cur ^= 1;
        }
    }
    #undef SLOAD
    #undef SWRITE

    #pragma unroll
    for (int i = 0; i < 2; ++i) {
        int mb = w * 32 + i * 16 + quad * 4;
        #pragma unroll
        for (int j = 0; j < 2; ++j) {
            int col = s0 + j * 16 + ln;
            #pragma unroll
            for (int r = 0; r < 4; ++r) {
                int m = mb + r;
                out[((size_t)b * CS + m0 + m) * S_ + col] = acc[i][j][r] + sBias[m];
            }
        }
    }
}

extern "C" void kernel_launch(void* const* d_in, const int* in_sizes, int n_in,
                              void* d_out, int out_size, void* d_ws, size_t ws_size,
                              hipStream_t stream) {
    const float* qxyz  = (const float*)d_in[0];
    const float* rxyz  = (const float*)d_in[1];
    const float* rfeat = (const float*)d_in[2];
    const float* seed  = (const float*)d_in[3];
    const float* Wseed = (const float*)d_in[4];
    const float* bseed = (const float*)d_in[5];
    const float* Wcat  = (const float*)d_in[6];
    const float* bcat  = (const float*)d_in[7];
    float* out = (float*)d_out;

    char* ws = (char*)d_ws;
    float* pval           = (float*)(ws);                        // 256 KB
    int* pidx             = (int*)(ws + 262144);                 // 256 KB
    float* beff           = (float*)(ws + 524288);               // 1 KB
    float4* refpk         = (float4*)(ws + 528384);              // 512 KB
    unsigned short* Wcomb = (unsigned short*)(ws + 1052672);     // 384 KB
    unsigned short* refT  = (unsigned short*)(ws + 1445888);     // 32 MB -> end 33.4 MB

    hipLaunchKernelGGL(prep_kernel, dim3(288), dim3(256), 0, stream,
                       rxyz, refpk, Wcat, Wseed, Wcomb, bseed, bcat, beff);
    hipLaunchKernelGGL(mid_kernel, dim3(4608), dim3(256), 0, stream,
                       qxyz, refpk, pval, pidx, rfeat, refT);
    hipLaunchKernelGGL(fused_gemm_kernel, dim3(128, 2, 4), dim3(256), 0, stream,
                       Wcomb, seed, refT, pval, pidx, beff, out);
}